// Round 1
// baseline (52.035 us; speedup 1.0000x reference)
//
#include <hip/hip_runtime.h>

#define IN_DIM   256
#define OUT_DIM  128
#define IN_SEQ   512
#define OUT_SEQ  512
#define NUM_BASIS 16
#define LN_EPS   1e-5f

// ---------------------------------------------------------------------------
// Kernel A: Z = x @ M.T (one block per sequence position k), then LayerNorm.
// Writes Zn[k][j] (row major, coalesced) and ZT[j][k] (transposed pre-LN Z,
// so kernel B's epilogue can read Z columns coalesced).
// ---------------------------------------------------------------------------
__global__ __launch_bounds__(256) void kA(const float* __restrict__ x,
                                          const float* __restrict__ M,
                                          const float* __restrict__ gamma,
                                          const float* __restrict__ beta,
                                          float* __restrict__ Zn,
                                          float* __restrict__ ZT) {
  const int k = blockIdx.x;
  const int t = threadIdx.x;
  __shared__ __align__(16) float xk[IN_DIM];
  __shared__ float red[256];
  __shared__ float stats[8];

  xk[t] = x[k * IN_DIM + t];
  __syncthreads();

  const int j = t & 127;
  const int h = t >> 7;  // which half of the 256-dim input
  const float4* __restrict__ M4 = reinterpret_cast<const float4*>(M + j * IN_DIM + h * 128);
  const float4* __restrict__ x4 = reinterpret_cast<const float4*>(xk + h * 128);
  float acc = 0.f;
#pragma unroll 8
  for (int c = 0; c < 32; ++c) {
    float4 m = M4[c];
    float4 xv = x4[c];
    acc = fmaf(m.x, xv.x, acc);
    acc = fmaf(m.y, xv.y, acc);
    acc = fmaf(m.z, xv.z, acc);
    acc = fmaf(m.w, xv.w, acc);
  }
  red[t] = acc;
  __syncthreads();

  float z = 0.f;
  if (t < 128) z = red[t] + red[t + 128];

  // LN statistics: reduce over j=0..127 (lives in waves 0,1; waves 2,3 add 0)
  float s1 = (t < 128) ? z : 0.f;
  float s2 = (t < 128) ? z * z : 0.f;
#pragma unroll
  for (int m = 1; m < 64; m <<= 1) {
    s1 += __shfl_xor(s1, m);
    s2 += __shfl_xor(s2, m);
  }
  const int w = t >> 6;
  if ((t & 63) == 0) {
    stats[w] = s1;
    stats[4 + w] = s2;
  }
  __syncthreads();
  const float mu  = (stats[0] + stats[1] + stats[2] + stats[3]) * (1.f / 128.f);
  const float msq = (stats[4] + stats[5] + stats[6] + stats[7]) * (1.f / 128.f);
  const float rs  = rsqrtf(msq - mu * mu + LN_EPS);

  if (t < 128) {
    float zn = (z - mu) * rs * gamma[t] + beta[t];
    Zn[k * OUT_DIM + t] = zn;     // coalesced
    ZT[t * IN_SEQ + k] = z;       // scattered 4B, tiny total
  }
}

// ---------------------------------------------------------------------------
// Kernel B: T[k,i] = sum_{j,g} Zn[k,j] * P[i,j,g] * cos(2*pi*k / p(i,j,g))
// p(i,j,g) = i*2048 + j*16 + g + 2. Block = (i, 64-k chunk), 256 threads:
// thread = (k-local 0..63, j-quarter 0..3). P-weight + 1/p pairs in LDS
// (uniform-address ds_read_b64 broadcast). Zn chunk in LDS, stride 129
// (lane l reads row l, column j uniform -> banks (l+j)%32, conflict-free).
// cos computed in revolutions: c = v_cos(v_fract(k * (1/p))).
// Epilogue writes V[k][i] = T[k,i] + Z[k,i].
// ---------------------------------------------------------------------------
__global__ __launch_bounds__(256) void kB(const float* __restrict__ P,
                                          const float* __restrict__ Zn,
                                          const float* __restrict__ ZT,
                                          float* __restrict__ V) {
  const int i  = blockIdx.y;        // output channel 0..127
  const int k0 = blockIdx.x * 64;   // k chunk base
  const int t  = threadIdx.x;

  __shared__ float2 pairs[OUT_DIM * NUM_BASIS];  // (P[i,j,g], 1/p) 16KB
  __shared__ float zn_lds[64 * 129];             // 32.25KB
  __shared__ float red[64 * 5];

  // stage P row i and reciprocal periods
  const float* __restrict__ Pi = P + i * (OUT_DIM * NUM_BASIS);
  const int pbase = i * (OUT_DIM * NUM_BASIS) + 2;
#pragma unroll
  for (int e = t; e < OUT_DIM * NUM_BASIS; e += 256) {
    float pw = Pi[e];
    float pinv = 1.0f / (float)(pbase + e);
    pairs[e] = make_float2(pw, pinv);
  }
  // stage Zn rows k0..k0+63 (all 128 j), padded stride 129
#pragma unroll
  for (int m = 0; m < 32; ++m) {
    int idx = m * 256 + t;          // 0..8191
    int r = idx >> 7;
    int j = idx & 127;
    zn_lds[r * 129 + j] = Zn[(k0 + r) * OUT_DIM + j];
  }
  __syncthreads();

  const int kl = t & 63;
  const int jq = t >> 6;
  const float kf = (float)(k0 + kl);
  const float* __restrict__ znrow = zn_lds + kl * 129;

  float acc = 0.f;
  for (int j = jq * 32; j < jq * 32 + 32; ++j) {
    float z = znrow[j];
    const float2* __restrict__ pp = pairs + j * NUM_BASIS;
    float accj = 0.f;
#pragma unroll
    for (int g = 0; g < NUM_BASIS; ++g) {
      float2 wv = pp[g];
      float ang = kf * wv.y;                    // revolutions
      float fr  = __builtin_amdgcn_fractf(ang); // [0,1)
      float c   = __builtin_amdgcn_cosf(fr);    // cos(2*pi*fr)
      accj = fmaf(wv.x, c, accj);
    }
    acc = fmaf(z, accj, acc);
  }

  red[kl * 5 + jq] = acc;
  __syncthreads();
  if (t < 64) {
    float s = red[t * 5 + 0] + red[t * 5 + 1] + red[t * 5 + 2] + red[t * 5 + 3];
    const int k = k0 + t;
    V[k * OUT_DIM + i] = s + ZT[i * IN_SEQ + k];  // T + pre-LN residual source
  }
}

// ---------------------------------------------------------------------------
// Kernel C: out[s,i] += sum_{k in chunk} Linker[k,s] * V[k,i]
// Block covers (2 s-values x 128 i); grid.y splits k into 4 for occupancy.
// L[k*512+s] is wave-uniform (1 fetch), V row read coalesced.
// ---------------------------------------------------------------------------
__global__ __launch_bounds__(256) void kC(const float* __restrict__ L,
                                          const float* __restrict__ V,
                                          float* __restrict__ out) {
  const int t = threadIdx.x;
  const int s = blockIdx.x * 2 + (t >> 7);
  const int i = t & 127;
  const int k0 = blockIdx.y * 128;
  float acc = 0.f;
#pragma unroll 8
  for (int kk = 0; kk < 128; ++kk) {
    const int k = k0 + kk;
    acc = fmaf(L[k * OUT_SEQ + s], V[k * OUT_DIM + i], acc);
  }
  atomicAdd(&out[s * OUT_DIM + i], acc);
}

extern "C" void kernel_launch(void* const* d_in, const int* in_sizes, int n_in,
                              void* d_out, int out_size, void* d_ws, size_t ws_size,
                              hipStream_t stream) {
  const float* x      = (const float*)d_in[0];
  const float* M      = (const float*)d_in[1];
  const float* P      = (const float*)d_in[2];
  const float* Linker = (const float*)d_in[3];
  const float* gamma  = (const float*)d_in[4];
  const float* beta   = (const float*)d_in[5];
  // d_in[6] = periods (recomputed inline: p = i*2048 + j*16 + g + 2, exact in f32)
  float* out = (float*)d_out;

  float* ws = (float*)d_ws;
  float* Zn = ws;                        // 512*128
  float* ZT = ws + IN_SEQ * OUT_DIM;     // 128*512 (pre-LN Z, transposed)
  float* V  = ws + 2 * IN_SEQ * OUT_DIM; // 512*128 (T + Z)

  hipMemsetAsync(d_out, 0, (size_t)out_size * sizeof(float), stream);

  kA<<<dim3(IN_SEQ), dim3(256), 0, stream>>>(x, M, gamma, beta, Zn, ZT);
  kB<<<dim3(8, OUT_DIM), dim3(256), 0, stream>>>(P, Zn, ZT, V);
  kC<<<dim3(OUT_SEQ / 2, 4), dim3(256), 0, stream>>>(Linker, V, out);
}

// Round 2
// 43.964 us; speedup vs baseline: 1.1836x; 1.1836x over previous
//
#include <hip/hip_runtime.h>

#define IN_DIM   256
#define OUT_DIM  128
#define IN_SEQ   512
#define OUT_SEQ  512
#define NUM_BASIS 16
#define LN_EPS   1e-5f

// ---------------------------------------------------------------------------
// Kernel A: Z = x @ M.T (one block per sequence position k), then LayerNorm.
// Writes Zn[k][j] (row major, coalesced) and ZT[j][k] (transposed pre-LN Z,
// so kernel B's epilogue can read Z columns coalesced).
// ---------------------------------------------------------------------------
__global__ __launch_bounds__(256) void kA(const float* __restrict__ x,
                                          const float* __restrict__ M,
                                          const float* __restrict__ gamma,
                                          const float* __restrict__ beta,
                                          float* __restrict__ Zn,
                                          float* __restrict__ ZT) {
  const int k = blockIdx.x;
  const int t = threadIdx.x;
  __shared__ __align__(16) float xk[IN_DIM];
  __shared__ float red[256];
  __shared__ float stats[8];

  xk[t] = x[k * IN_DIM + t];
  __syncthreads();

  const int j = t & 127;
  const int h = t >> 7;  // which half of the 256-dim input
  const float4* __restrict__ M4 = reinterpret_cast<const float4*>(M + j * IN_DIM + h * 128);
  const float4* __restrict__ x4 = reinterpret_cast<const float4*>(xk + h * 128);
  float acc = 0.f;
#pragma unroll 8
  for (int c = 0; c < 32; ++c) {
    float4 m = M4[c];
    float4 xv = x4[c];
    acc = fmaf(m.x, xv.x, acc);
    acc = fmaf(m.y, xv.y, acc);
    acc = fmaf(m.z, xv.z, acc);
    acc = fmaf(m.w, xv.w, acc);
  }
  red[t] = acc;
  __syncthreads();

  float z = 0.f;
  if (t < 128) z = red[t] + red[t + 128];

  // LN statistics: reduce over j=0..127 (lives in waves 0,1; waves 2,3 add 0)
  float s1 = (t < 128) ? z : 0.f;
  float s2 = (t < 128) ? z * z : 0.f;
#pragma unroll
  for (int m = 1; m < 64; m <<= 1) {
    s1 += __shfl_xor(s1, m);
    s2 += __shfl_xor(s2, m);
  }
  const int w = t >> 6;
  if ((t & 63) == 0) {
    stats[w] = s1;
    stats[4 + w] = s2;
  }
  __syncthreads();
  const float mu  = (stats[0] + stats[1] + stats[2] + stats[3]) * (1.f / 128.f);
  const float msq = (stats[4] + stats[5] + stats[6] + stats[7]) * (1.f / 128.f);
  const float rs  = rsqrtf(msq - mu * mu + LN_EPS);

  if (t < 128) {
    float zn = (z - mu) * rs * gamma[t] + beta[t];
    Zn[k * OUT_DIM + t] = zn;     // coalesced
    ZT[t * IN_SEQ + k] = z;       // scattered 4B, tiny total
  }
}

// ---------------------------------------------------------------------------
// Kernel B: T[k,i] = sum_{j,g} Zn[k,j] * P[i,j,g] * cos(2*pi*k / p(i,j,g))
// p(i,j,g) = i*2048 + j*16 + g + 2. Block = (i, 64-k chunk), 256 threads:
// thread = (k-local 0..63, j-quarter 0..3). P-weight + 1/p pairs in LDS
// (uniform-address ds_read_b64 broadcast). Zn chunk in LDS, stride 129
// (lane l reads row l, column j uniform -> banks (l+j)%32, conflict-free).
// cos computed in revolutions: c = v_cos(v_fract(k * (1/p))).
// Epilogue writes V[k][i] = T[k,i] + Z[k,i].
// ---------------------------------------------------------------------------
__global__ __launch_bounds__(256) void kB(const float* __restrict__ P,
                                          const float* __restrict__ Zn,
                                          const float* __restrict__ ZT,
                                          float* __restrict__ V) {
  const int i  = blockIdx.y;        // output channel 0..127
  const int k0 = blockIdx.x * 64;   // k chunk base
  const int t  = threadIdx.x;

  __shared__ float2 pairs[OUT_DIM * NUM_BASIS];  // (P[i,j,g], 1/p) 16KB
  __shared__ float zn_lds[64 * 129];             // 32.25KB
  __shared__ float red[64 * 5];

  // stage P row i and reciprocal periods
  const float* __restrict__ Pi = P + i * (OUT_DIM * NUM_BASIS);
  const int pbase = i * (OUT_DIM * NUM_BASIS) + 2;
#pragma unroll
  for (int e = t; e < OUT_DIM * NUM_BASIS; e += 256) {
    float pw = Pi[e];
    float pinv = 1.0f / (float)(pbase + e);
    pairs[e] = make_float2(pw, pinv);
  }
  // stage Zn rows k0..k0+63 (all 128 j), padded stride 129
#pragma unroll
  for (int m = 0; m < 32; ++m) {
    int idx = m * 256 + t;          // 0..8191
    int r = idx >> 7;
    int j = idx & 127;
    zn_lds[r * 129 + j] = Zn[(k0 + r) * OUT_DIM + j];
  }
  __syncthreads();

  const int kl = t & 63;
  const int jq = t >> 6;
  const float kf = (float)(k0 + kl);
  const float* __restrict__ znrow = zn_lds + kl * 129;

  float acc = 0.f;
  for (int j = jq * 32; j < jq * 32 + 32; ++j) {
    float z = znrow[j];
    const float2* __restrict__ pp = pairs + j * NUM_BASIS;
    float accj = 0.f;
#pragma unroll
    for (int g = 0; g < NUM_BASIS; ++g) {
      float2 wv = pp[g];
      float ang = kf * wv.y;                    // revolutions
      float fr  = __builtin_amdgcn_fractf(ang); // [0,1)
      float c   = __builtin_amdgcn_cosf(fr);    // cos(2*pi*fr)
      accj = fmaf(wv.x, c, accj);
    }
    acc = fmaf(z, accj, acc);
  }

  red[kl * 5 + jq] = acc;
  __syncthreads();
  if (t < 64) {
    float s = red[t * 5 + 0] + red[t * 5 + 1] + red[t * 5 + 2] + red[t * 5 + 3];
    const int k = k0 + t;
    V[k * OUT_DIM + i] = s + ZT[i * IN_SEQ + k];  // T + pre-LN residual source
  }
}

// ---------------------------------------------------------------------------
// Kernel C: out[s,:] = sum_k Linker[k,s] * V[k,:]  — one block per s.
// 512 threads = 4 k-quarters x 128 i. L column staged in LDS (coalesced-ish
// one-time strided load, then uniform broadcast reads). 4 partials reduced
// through LDS. Direct store — no atomics, no zero-init needed.
// ---------------------------------------------------------------------------
__global__ __launch_bounds__(512) void kC(const float* __restrict__ L,
                                          const float* __restrict__ V,
                                          float* __restrict__ out) {
  const int s = blockIdx.x;
  const int t = threadIdx.x;
  const int i = t & 127;
  const int q = t >> 7;  // k-quarter 0..3
  __shared__ float Lcol[IN_SEQ];
  __shared__ float red[4 * OUT_DIM];

  Lcol[t] = L[t * OUT_SEQ + s];
  __syncthreads();

  const int k0 = q * 128;
  float acc = 0.f;
#pragma unroll 8
  for (int kk = 0; kk < 128; ++kk) {
    const int k = k0 + kk;
    acc = fmaf(Lcol[k], V[k * OUT_DIM + i], acc);
  }
  red[q * OUT_DIM + i] = acc;
  __syncthreads();

  if (t < OUT_DIM) {
    out[s * OUT_DIM + t] =
        red[t] + red[OUT_DIM + t] + red[2 * OUT_DIM + t] + red[3 * OUT_DIM + t];
  }
}

extern "C" void kernel_launch(void* const* d_in, const int* in_sizes, int n_in,
                              void* d_out, int out_size, void* d_ws, size_t ws_size,
                              hipStream_t stream) {
  const float* x      = (const float*)d_in[0];
  const float* M      = (const float*)d_in[1];
  const float* P      = (const float*)d_in[2];
  const float* Linker = (const float*)d_in[3];
  const float* gamma  = (const float*)d_in[4];
  const float* beta   = (const float*)d_in[5];
  // d_in[6] = periods (recomputed inline: p = i*2048 + j*16 + g + 2, exact in f32)
  float* out = (float*)d_out;

  float* ws = (float*)d_ws;
  float* Zn = ws;                        // 512*128
  float* ZT = ws + IN_SEQ * OUT_DIM;     // 128*512 (pre-LN Z, transposed)
  float* V  = ws + 2 * IN_SEQ * OUT_DIM; // 512*128 (T + Z)

  kA<<<dim3(IN_SEQ), dim3(256), 0, stream>>>(x, M, gamma, beta, Zn, ZT);
  kB<<<dim3(8, OUT_DIM), dim3(256), 0, stream>>>(P, Zn, ZT, V);
  kC<<<dim3(OUT_SEQ), dim3(512), 0, stream>>>(Linker, V, out);
}

// Round 3
// 43.317 us; speedup vs baseline: 1.2013x; 1.0149x over previous
//
#include <hip/hip_runtime.h>

#define IN_DIM   256
#define OUT_DIM  128
#define IN_SEQ   512
#define OUT_SEQ  512
#define NUM_BASIS 16
#define LN_EPS   1e-5f
#define KC       64   // k-chunk length per kB block

__device__ __forceinline__ float cosrev(float x) {
  // cos(2*pi*x) for any x: v_fract then v_cos (revolutions semantics)
  return __builtin_amdgcn_cosf(__builtin_amdgcn_fractf(x));
}

// ---------------------------------------------------------------------------
// Kernel A: Z = x @ M.T (one block per sequence position k), then LayerNorm.
// Writes Zn[k][j] (row major, coalesced) and ZT[j][k] (transposed pre-LN Z,
// read coalesced by kB's epilogue).
// ---------------------------------------------------------------------------
__global__ __launch_bounds__(256) void kA(const float* __restrict__ x,
                                          const float* __restrict__ M,
                                          const float* __restrict__ gamma,
                                          const float* __restrict__ beta,
                                          float* __restrict__ Zn,
                                          float* __restrict__ ZT) {
  const int k = blockIdx.x;
  const int t = threadIdx.x;
  __shared__ __align__(16) float xk[IN_DIM];
  __shared__ float red[256];
  __shared__ float stats[8];

  xk[t] = x[k * IN_DIM + t];
  __syncthreads();

  const int j = t & 127;
  const int h = t >> 7;  // which half of the 256-dim input
  const float4* __restrict__ M4 = reinterpret_cast<const float4*>(M + j * IN_DIM + h * 128);
  const float4* __restrict__ x4 = reinterpret_cast<const float4*>(xk + h * 128);
  float acc = 0.f;
#pragma unroll 8
  for (int c = 0; c < 32; ++c) {
    float4 m = M4[c];
    float4 xv = x4[c];
    acc = fmaf(m.x, xv.x, acc);
    acc = fmaf(m.y, xv.y, acc);
    acc = fmaf(m.z, xv.z, acc);
    acc = fmaf(m.w, xv.w, acc);
  }
  red[t] = acc;
  __syncthreads();

  float z = 0.f;
  if (t < 128) z = red[t] + red[t + 128];

  float s1 = (t < 128) ? z : 0.f;
  float s2 = (t < 128) ? z * z : 0.f;
#pragma unroll
  for (int m = 1; m < 64; m <<= 1) {
    s1 += __shfl_xor(s1, m);
    s2 += __shfl_xor(s2, m);
  }
  const int w = t >> 6;
  if ((t & 63) == 0) {
    stats[w] = s1;
    stats[4 + w] = s2;
  }
  __syncthreads();
  const float mu  = (stats[0] + stats[1] + stats[2] + stats[3]) * (1.f / 128.f);
  const float msq = (stats[4] + stats[5] + stats[6] + stats[7]) * (1.f / 128.f);
  const float rs  = rsqrtf(msq - mu * mu + LN_EPS);

  if (t < 128) {
    float zn = (z - mu) * rs * gamma[t] + beta[t];
    Zn[k * OUT_DIM + t] = zn;     // coalesced
    ZT[t * IN_SEQ + k] = z;       // scattered 4B, tiny total
  }
}

// ---------------------------------------------------------------------------
// Kernel B (Chebyshev recurrence): T[k,i] = sum_{j,g} Zn[k,j]*P[i,j,g]*c(k)
// where c(k) = cos(2*pi*k/p), p = i*2048 + j*16 + g + 2.
// c(k+1) = 2cos(2*pi/p)*c(k) - c(k-1)  -> 1 FMA per element per k instead of
// mul+fract+cos(quarter-rate)+fma.  Block = (i, KC-k chunk), 128 threads =
// one j each, 16 g-recurrences per thread in registers.
// Per k: 16 FMA (P*c) + 1 mul (Zn) + 6 shfl (wave reduce) + 16 FMA (advance).
// Wave partials land in LDS (no per-k sync); epilogue sums 2 waves and adds
// the pre-LN residual: V[k][i] = T[k,i] + Z[k,i].
// ---------------------------------------------------------------------------
__global__ __launch_bounds__(128) void kB(const float* __restrict__ P,
                                          const float* __restrict__ Zn,
                                          const float* __restrict__ ZT,
                                          float* __restrict__ V) {
  const int i  = blockIdx.y;        // output channel 0..127
  const int k0 = blockIdx.x * KC;   // k chunk base
  const int j  = threadIdx.x;       // 0..127
  const int w  = j >> 6;            // wave id 0/1

  __shared__ float red[KC * 2];

  // --- per-(i,j,g) state: P weight, 2cos(theta), c(k0-1), c(k0) ---
  float Pv[NUM_BASIS], tc[NUM_BASIS], c0[NUM_BASIS], c1[NUM_BASIS];
  {
    const float4* __restrict__ P4 =
        reinterpret_cast<const float4*>(P + (size_t)(i * OUT_DIM + j) * NUM_BASIS);
    float4 pl[4] = {P4[0], P4[1], P4[2], P4[3]};
#pragma unroll
    for (int q = 0; q < 4; ++q) {
      Pv[4 * q + 0] = pl[q].x;
      Pv[4 * q + 1] = pl[q].y;
      Pv[4 * q + 2] = pl[q].z;
      Pv[4 * q + 3] = pl[q].w;
    }
  }
  const int pb = i * (OUT_DIM * NUM_BASIS) + j * NUM_BASIS + 2;
  const float km1 = (float)(k0 - 1);   // k0=0 -> fract(-pinv) = 1-pinv, cos even: OK
  const float kcu = (float)k0;
#pragma unroll
  for (int g = 0; g < NUM_BASIS; ++g) {
    float pinv = 1.0f / (float)(pb + g);            // p >= 2 -> pinv <= 0.5
    tc[g] = 2.0f * __builtin_amdgcn_cosf(pinv);     // 2*cos(2*pi/p)
    c0[g] = cosrev(km1 * pinv);
    c1[g] = cosrev(kcu * pinv);
  }

  // --- main k loop, unrolled by 4 with one-group-ahead Zn prefetch ---
  const float* __restrict__ znj = Zn + j;   // Zn[k][j] = znj[k*OUT_DIM], coalesced per k
  float buf[4];
#pragma unroll
  for (int r = 0; r < 4; ++r) buf[r] = znj[(k0 + r) * OUT_DIM];

  for (int kg = 0; kg < KC / 4; ++kg) {
    float nbuf[4];
#pragma unroll
    for (int r = 0; r < 4; ++r) {
      // last group prefetches k0+KC..k0+KC+3; for the final chunk this reads
      // into the adjacent ZT region of the same workspace (values unused).
      nbuf[r] = znj[(k0 + (kg + 1) * 4 + r) * OUT_DIM];
    }
#pragma unroll
    for (int r = 0; r < 4; ++r) {
      float s = 0.f;
#pragma unroll
      for (int g = 0; g < NUM_BASIS; ++g) s = fmaf(Pv[g], c1[g], s);
      float v = buf[r] * s;
#pragma unroll
      for (int m = 1; m < 64; m <<= 1) v += __shfl_xor(v, m);
      if ((j & 63) == 0) red[(kg * 4 + r) * 2 + w] = v;
#pragma unroll
      for (int g = 0; g < NUM_BASIS; ++g) {
        float cn = fmaf(tc[g], c1[g], -c0[g]);
        c0[g] = c1[g];
        c1[g] = cn;
      }
    }
#pragma unroll
    for (int r = 0; r < 4; ++r) buf[r] = nbuf[r];
  }

  __syncthreads();
  if (j < KC) {
    const int k = k0 + j;
    V[k * OUT_DIM + i] = red[j * 2] + red[j * 2 + 1] + ZT[i * IN_SEQ + k];
  }
}

// ---------------------------------------------------------------------------
// Kernel C: out[s,:] = sum_k Linker[k,s] * V[k,:]  — one block per s.
// 512 threads = 4 k-quarters x 128 i. L column staged in LDS, 4 partials
// reduced through LDS. Direct store — no atomics, no zero-init needed.
// ---------------------------------------------------------------------------
__global__ __launch_bounds__(512) void kC(const float* __restrict__ L,
                                          const float* __restrict__ V,
                                          float* __restrict__ out) {
  const int s = blockIdx.x;
  const int t = threadIdx.x;
  const int i = t & 127;
  const int q = t >> 7;  // k-quarter 0..3
  __shared__ float Lcol[IN_SEQ];
  __shared__ float red[4 * OUT_DIM];

  Lcol[t] = L[t * OUT_SEQ + s];
  __syncthreads();

  const int k0 = q * 128;
  float acc = 0.f;
#pragma unroll 8
  for (int kk = 0; kk < 128; ++kk) {
    const int k = k0 + kk;
    acc = fmaf(Lcol[k], V[k * OUT_DIM + i], acc);
  }
  red[q * OUT_DIM + i] = acc;
  __syncthreads();

  if (t < OUT_DIM) {
    out[s * OUT_DIM + t] =
        red[t] + red[OUT_DIM + t] + red[2 * OUT_DIM + t] + red[3 * OUT_DIM + t];
  }
}

extern "C" void kernel_launch(void* const* d_in, const int* in_sizes, int n_in,
                              void* d_out, int out_size, void* d_ws, size_t ws_size,
                              hipStream_t stream) {
  const float* x      = (const float*)d_in[0];
  const float* M      = (const float*)d_in[1];
  const float* P      = (const float*)d_in[2];
  const float* Linker = (const float*)d_in[3];
  const float* gamma  = (const float*)d_in[4];
  const float* beta   = (const float*)d_in[5];
  // d_in[6] = periods (recomputed inline: p = i*2048 + j*16 + g + 2, exact in f32)
  float* out = (float*)d_out;

  float* ws = (float*)d_ws;
  float* Zn = ws;                        // 512*128
  float* ZT = ws + IN_SEQ * OUT_DIM;     // 128*512 (pre-LN Z, transposed)
  float* V  = ws + 2 * IN_SEQ * OUT_DIM; // 512*128 (T + Z)

  kA<<<dim3(IN_SEQ), dim3(256), 0, stream>>>(x, M, gamma, beta, Zn, ZT);
  kB<<<dim3(IN_SEQ / KC, OUT_DIM), dim3(128), 0, stream>>>(P, Zn, ZT, V);
  kC<<<dim3(OUT_SEQ), dim3(512), 0, stream>>>(Linker, V, out);
}